// Round 1
// baseline (593.782 us; speedup 1.0000x reference)
//
#include <hip/hip_runtime.h>
#include <hip/hip_bf16.h>
#include <math.h>

#define N_NODES 100000
#define N_EDGES 3200000
#define IN_F    512
#define HID     16
#define NCLS    40

// ---------------- dtype sniffing for edge_index ------------------------------
// Reference declares int64, harness doc says "integer -> const int*".
// Detect at runtime: if the buffer is int64 (values < 2^31), every odd int32
// word (high half) is 0. For an int32 buffer, odd words are real edge ids,
// uniform in [0,1e5) -> P(1024 sampled all zero) ~ 0. Deterministic.
__global__ __launch_bounds__(256) void k_detect(const int* __restrict__ ei,
                                                int* __restrict__ flag) {
    __shared__ int s_nz;
    if (threadIdx.x == 0) s_nz = 0;
    __syncthreads();
    int nz = 0;
    for (int i = threadIdx.x; i < 1024; i += 256)
        if (ei[2 * i + 1] != 0) nz = 1;
    if (nz) atomicOr(&s_nz, 1);
    __syncthreads();
    if (threadIdx.x == 0) flag[0] = s_nz ? 0 : 1;  // 1 => int64 layout
}

__device__ __forceinline__ int load_edge(const void* ei, int is64, int idx) {
    if (is64) return (int)((const long long*)ei)[idx];
    return ((const int*)ei)[idx];
}

// ---------------- degree / dinv ----------------------------------------------
__global__ __launch_bounds__(256) void k_init_deg(float* __restrict__ deg) {
    int n = blockIdx.x * 256 + threadIdx.x;
    if (n < N_NODES) deg[n] = 1.0f;  // self loop
}

__global__ __launch_bounds__(256) void k_deg(const void* __restrict__ ei,
                                             const int* __restrict__ flag,
                                             float* __restrict__ deg) {
    int e = blockIdx.x * 256 + threadIdx.x;
    if (e >= N_EDGES) return;
    int d = load_edge(ei, flag[0], N_EDGES + e);
    atomicAdd(&deg[d], 1.0f);
}

__global__ __launch_bounds__(256) void k_dinv(const float* __restrict__ deg,
                                              float* __restrict__ dinv) {
    int n = blockIdx.x * 256 + threadIdx.x;
    if (n < N_NODES) dinv[n] = rsqrtf(deg[n]);
}

// ---------------- layer 1 GEMM: h = x @ W1, agg1 = h * dinv^2 ----------------
__global__ __launch_bounds__(256) void k_gemm1(const float* __restrict__ x,
                                               const float* __restrict__ W1,
                                               const float* __restrict__ dinv,
                                               float* __restrict__ h,
                                               float* __restrict__ agg1) {
    __shared__ float Ws[IN_F * HID];  // 32 KB
    for (int i = threadIdx.x; i < IN_F * HID; i += 256) Ws[i] = W1[i];
    __syncthreads();
    int n = blockIdx.x * 256 + threadIdx.x;
    if (n >= N_NODES) return;
    float acc[HID];
#pragma unroll
    for (int j = 0; j < HID; ++j) acc[j] = 0.0f;
    const float4* xr = (const float4*)(x + (size_t)n * IN_F);
    for (int k4 = 0; k4 < IN_F / 4; ++k4) {
        float4 xv = xr[k4];
        int kb = k4 * 4;
#pragma unroll
        for (int i = 0; i < 4; ++i) {
            float xs = (&xv.x)[i];
            const float4* wr = (const float4*)(Ws + (kb + i) * HID);
#pragma unroll
            for (int j4 = 0; j4 < 4; ++j4) {
                float4 w = wr[j4];  // same addr across lanes -> LDS broadcast
                acc[j4 * 4 + 0] += xs * w.x;
                acc[j4 * 4 + 1] += xs * w.y;
                acc[j4 * 4 + 2] += xs * w.z;
                acc[j4 * 4 + 3] += xs * w.w;
            }
        }
    }
    float di = dinv[n];
    float sl = di * di;  // self-loop norm
    float* hn = h + n * HID;
    float* an = agg1 + n * HID;
#pragma unroll
    for (int j = 0; j < HID; ++j) {
        hn[j] = acc[j];
        an[j] = acc[j] * sl;
    }
}

// ---------------- edge scatter: agg[dst] += feat[src] * dinv[s]*dinv[d] ------
__global__ __launch_bounds__(256) void k_scatter(const void* __restrict__ ei,
                                                 const int* __restrict__ flag,
                                                 const float* __restrict__ feat,
                                                 const float* __restrict__ dinv,
                                                 float* __restrict__ agg) {
    unsigned t = blockIdx.x * 256u + threadIdx.x;
    unsigned e = t >> 4;
    int j = (int)(t & 15u);
    if (e >= N_EDGES) return;
    int is64 = flag[0];
    int s = load_edge(ei, is64, (int)e);
    int d = load_edge(ei, is64, N_EDGES + (int)e);
    float nrm = dinv[s] * dinv[d];
    atomicAdd(&agg[d * HID + j], feat[s * HID + j] * nrm);
}

// ---------------- relu(agg1+b1) -> h1 ; agg2 = h1*dinv^2 ---------------------
__global__ __launch_bounds__(256) void k_relu(const float* __restrict__ agg1,
                                              const float* __restrict__ b1,
                                              const float* __restrict__ dinv,
                                              float* __restrict__ h1,
                                              float* __restrict__ agg2) {
    int t = blockIdx.x * 256 + threadIdx.x;
    if (t >= N_NODES * HID) return;
    int n = t >> 4;
    int j = t & 15;
    float v = agg1[t] + b1[j];
    v = fmaxf(v, 0.0f);
    h1[t] = v;
    float di = dinv[n];
    agg2[t] = v * di * di;
}

// ---------------- out = log_softmax(agg2 @ W2 + b2) --------------------------
__global__ __launch_bounds__(256) void k_out(const float* __restrict__ agg2,
                                             const float* __restrict__ W2,
                                             const float* __restrict__ b2,
                                             float* __restrict__ out) {
    __shared__ float Ws[HID * NCLS];  // 2.5 KB
    __shared__ float bs[NCLS];
    for (int i = threadIdx.x; i < HID * NCLS; i += 256) Ws[i] = W2[i];
    for (int i = threadIdx.x; i < NCLS; i += 256) bs[i] = b2[i];
    __syncthreads();
    int n = blockIdx.x * 256 + threadIdx.x;
    if (n >= N_NODES) return;
    float a[HID];
    const float4* ar = (const float4*)(agg2 + n * HID);
#pragma unroll
    for (int q = 0; q < HID / 4; ++q) {
        float4 v = ar[q];
        a[q * 4 + 0] = v.x; a[q * 4 + 1] = v.y;
        a[q * 4 + 2] = v.z; a[q * 4 + 3] = v.w;
    }
    float logits[NCLS];
#pragma unroll
    for (int c = 0; c < NCLS; ++c) logits[c] = bs[c];
#pragma unroll
    for (int k = 0; k < HID; ++k) {
        float av = a[k];
        const float* wr = Ws + k * NCLS;
#pragma unroll
        for (int c = 0; c < NCLS; ++c) logits[c] += av * wr[c];
    }
    float m = logits[0];
#pragma unroll
    for (int c = 1; c < NCLS; ++c) m = fmaxf(m, logits[c]);
    float ssum = 0.0f;
#pragma unroll
    for (int c = 0; c < NCLS; ++c) ssum += expf(logits[c] - m);
    float lse = m + logf(ssum);
    float* on = out + n * NCLS;
#pragma unroll
    for (int c = 0; c < NCLS; ++c) on[c] = logits[c] - lse;
}

// ---------------- launch -----------------------------------------------------
extern "C" void kernel_launch(void* const* d_in, const int* in_sizes, int n_in,
                              void* d_out, int out_size, void* d_ws, size_t ws_size,
                              hipStream_t stream) {
    const float* x  = (const float*)d_in[0];
    const void*  ei = d_in[1];
    const float* W1 = (const float*)d_in[2];
    const float* b1 = (const float*)d_in[3];
    const float* W2 = (const float*)d_in[4];
    const float* b2 = (const float*)d_in[5];
    float* out = (float*)d_out;

    float* ws   = (float*)d_ws;
    float* deg  = ws;                       // N
    float* dinv = ws + 100000;              // N
    float* h    = ws + 200000;              // N*16
    float* agg1 = ws + 1800000;             // N*16
    float* h1   = ws + 3400000;             // N*16
    float* agg2 = ws + 5000000;             // N*16
    int*   flag = (int*)(ws + 6600000);     // 1

    const int B = 256;
    int gN   = (N_NODES + B - 1) / B;            // 391
    int gE   = (N_EDGES + B - 1) / B;            // 12500
    int gNH  = (N_NODES * HID + B - 1) / B;      // 6250
    int gSC  = (int)(((long long)N_EDGES * HID + B - 1) / B);  // 200000

    k_detect<<<1, B, 0, stream>>>((const int*)ei, flag);
    k_init_deg<<<gN, B, 0, stream>>>(deg);
    k_deg<<<gE, B, 0, stream>>>(ei, flag, deg);
    k_dinv<<<gN, B, 0, stream>>>(deg, dinv);
    k_gemm1<<<gN, B, 0, stream>>>(x, W1, dinv, h, agg1);
    k_scatter<<<gSC, B, 0, stream>>>(ei, flag, h, dinv, agg1);
    k_relu<<<gNH, B, 0, stream>>>(agg1, b1, dinv, h1, agg2);
    k_scatter<<<gSC, B, 0, stream>>>(ei, flag, h1, dinv, agg2);
    k_out<<<gN, B, 0, stream>>>(agg2, W2, b2, out);
}